// Round 13
// baseline (276.313 us; speedup 1.0000x reference)
//
#include <hip/hip_runtime.h>

#define VOCAB 128
#define EMB   8
#define HID   32
#define BATCH 512
#define SEQ   512
#define G4    128   // 4*HID
#define KB    8     // recurrence steps per phase
#define WPB   8     // waves per block (2 per SIMD -> mutual stall hiding)

#define LOG2E 1.4426950408889634f

// ---------------------------------------------------------------------------
// Kernel 1: proj[v][r] = (dot(emb[v], w_ih[r]) + b_ih[r] + b_hh[r]) * rowscale
// rowscale folds exp->exp2: g-rows [64,96): 2*log2e ; others: log2e
// ---------------------------------------------------------------------------
__global__ void build_proj(const float* __restrict__ emb,
                           const float* __restrict__ w_ih,
                           const float* __restrict__ b_ih,
                           const float* __restrict__ b_hh,
                           float* __restrict__ proj) {
    int idx = blockIdx.x * blockDim.x + threadIdx.x;   // 0 .. 16383
    int v = idx >> 7;
    int r = idx & 127;
    float acc = b_ih[r] + b_hh[r];
#pragma unroll
    for (int e = 0; e < EMB; ++e)
        acc += emb[v * EMB + e] * w_ih[r * EMB + e];
    float sc = (r >= 64 && r < 96) ? (2.0f * LOG2E) : LOG2E;
    proj[v * G4 + r] = acc * sc;
}

// ---------------------------------------------------------------------------
// Fast gate nonlinearities (inputs pre-scaled by log2e / 2*log2e). Proven R10.
// ---------------------------------------------------------------------------
__device__ __forceinline__ float sig2(float x) {
    return __builtin_amdgcn_rcpf(1.0f + __builtin_amdgcn_exp2f(-x));
}
__device__ __forceinline__ float tanh2(float x2) {
    return 1.0f - 2.0f * __builtin_amdgcn_rcpf(__builtin_amdgcn_exp2f(x2) + 1.0f);
}

// ---------------------------------------------------------------------------
// Alias-proof half-broadcast (proven R10): early-clobber outputs guarantee
// distinct registers; after the swap, lo = low-half value broadcast to all
// lanes, hi = high-half value broadcast to all lanes.
// ---------------------------------------------------------------------------
__device__ __forceinline__ void half_bcast(float acc, float& lo, float& hi) {
    asm("v_mov_b32 %0, %2\n\t"
        "v_mov_b32 %1, %2\n\t"
        "v_permlane32_swap_b32 %0, %1"
        : "=&v"(lo), "=&v"(hi)
        : "v"(acc));
}

// ---------------------------------------------------------------------------
// Kernel 2: LSTM recurrence — R12's proven per-wave code, repacked as
// 8 waves per block (8 sequences, shared sproj). SINGLE DELTA vs R12:
// launch geometry. 2 waves land on each SIMD, so one wave's ~190 cyc/step
// dependency stall is filled by the other wave's issue.
// NOTE: waves_per_eu(1,1) REMOVED (it would cap 1 wave/SIMD);
// __launch_bounds__(512, 2) requests min 2 waves/EU (VGPR cap 256 > 132).
// ---------------------------------------------------------------------------
__global__ __launch_bounds__(512, 2)
void lstm_rec(
    const int*   __restrict__ tokens,   // [B][T]
    const float* __restrict__ w_hh,     // [128][32]
    const float* __restrict__ proj,     // [128][128], pre-scaled
    float*       __restrict__ h_out)    // [B*T][32]
{
    const int tid  = threadIdx.x;       // 0..511
    const int wv   = tid >> 6;          // wave 0..7
    const int lane = tid & 63;          // 0..63
    const int b    = blockIdx.x * WPB + wv;   // sequence id

    __shared__ float sproj[VOCAB * G4];   // 64 KB, shared by all 8 waves

    // ---- stage proj into LDS (all 512 threads) ----
    {
        const float4* src = (const float4*)proj;
        float4*       dst = (float4*)sproj;
#pragma unroll
        for (int i = 0; i < (VOCAB * G4 / 4) / 512; ++i)   // 8 iters
            dst[i * 512 + tid] = src[i * 512 + tid];
    }

    // ---- recurrent weights: 2 gate rows per lane, pre-scaled, pinned ----
    const float sc1 = (lane < 32) ? (2.0f * LOG2E) : LOG2E;
    float w0[HID], w1[HID];
#pragma unroll
    for (int j = 0; j < HID; ++j) {
        w0[j] = w_hh[lane * HID + j] * LOG2E;
        w1[j] = w_hh[(lane + 64) * HID + j] * sc1;
    }
#pragma unroll
    for (int j = 0; j < HID; ++j) {
        asm volatile("" : "+v"(w0[j]), "+v"(w1[j]));   // non-rematerializable
    }

    // ---- this wave's 512 tokens in lane registers ----
    // lane l holds tok[l*8 .. l*8+7]
    const int* tok = tokens + b * SEQ;
    int tv[KB];
    {
        int4 a = ((const int4*)tok)[lane * 2];
        int4 d = ((const int4*)tok)[lane * 2 + 1];
        tv[0] = a.x; tv[1] = a.y; tv[2] = a.z; tv[3] = a.w;
        tv[4] = d.x; tv[5] = d.y; tv[6] = d.z; tv[7] = d.w;
    }

    __syncthreads();

    float h = 0.0f, c = 0.0f;
    float* hp = h_out + (size_t)b * SEQ * HID + lane;   // lanes<32 store
    float hsave[KB];

    // xp double buffer in registers: xc = current block, xn = next block.
    float xc0[KB], xc1[KB];

    // prologue: load block 0 (tokens in lane 0)
#pragma unroll
    for (int k = 0; k < KB; ++k) {
        int tk = __builtin_amdgcn_readlane(tv[k], 0);
        xc0[k] = sproj[tk * G4 + lane];
        xc1[k] = sproj[tk * G4 + 64 + lane];
    }

    for (int t0 = 0; t0 < SEQ; t0 += KB) {
        // ---- phase A: issue next block's 16 ds_reads (wrap to 0 at tail) ----
        const int nb = t0 + KB;
        const int ln = (nb < SEQ) ? (nb >> 3) : 0;   // uniform lane index
        float xn0[KB], xn1[KB];
#pragma unroll
        for (int k = 0; k < KB; ++k) {
            int tk = __builtin_amdgcn_readlane(tv[k], ln);
            xn0[k] = sproj[tk * G4 + lane];
            xn1[k] = sproj[tk * G4 + 64 + lane];
        }
        __builtin_amdgcn_sched_barrier(0);   // loads may not sink below here

        // ---- phase B: 8 recurrence steps, pure register compute ----
#pragma unroll
        for (int k = 0; k < KB; ++k) {
            float s0 = xc0[k], s1 = 0.0f, s2 = 0.0f, s3 = 0.0f;  // row lane
            float u0 = xc1[k], u1 = 0.0f, u2 = 0.0f, u3 = 0.0f;  // row lane+64
            unsigned hb = __float_as_uint(h);
#pragma unroll
            for (int j = 0; j < HID; j += 4) {
                float h0 = __uint_as_float(__builtin_amdgcn_readlane(hb, j));
                float h1 = __uint_as_float(__builtin_amdgcn_readlane(hb, j + 1));
                float h2 = __uint_as_float(__builtin_amdgcn_readlane(hb, j + 2));
                float h3 = __uint_as_float(__builtin_amdgcn_readlane(hb, j + 3));
                s0 = fmaf(h0, w0[j],     s0);
                s1 = fmaf(h1, w0[j + 1], s1);
                s2 = fmaf(h2, w0[j + 2], s2);
                s3 = fmaf(h3, w0[j + 3], s3);
                u0 = fmaf(h0, w1[j],     u0);
                u1 = fmaf(h1, w1[j + 1], u1);
                u2 = fmaf(h2, w1[j + 2], u2);
                u3 = fmaf(h3, w1[j + 3], u3);
            }
            float acc0 = (s0 + s1) + (s2 + s3);  // i (lo lanes) | f (hi lanes)
            float acc1 = (u0 + u1) + (u2 + u3);  // g (lo, *2log2e) | o (hi)

            // ---- alias-proof half broadcast: iv/gv = lo, fv/ov = hi ----
            float iv, fv, gv, ov;
            half_bcast(acc0, iv, fv);
            half_bcast(acc1, gv, ov);

            // ---- nonlinearities (exp2-domain, hw rcp) ----
            c = sig2(fv) * c + sig2(iv) * tanh2(gv);
            h = sig2(ov) * tanh2(c * (2.0f * LOG2E));

            hsave[k] = h;
        }

        // ---- phase C: flush h stores (no vmcnt wait inside the loop) ----
        if (lane < 32) {
#pragma unroll
            for (int k = 0; k < KB; ++k)
                hp[(size_t)(t0 + k) * HID] = hsave[k];
        }

        // ---- phase D: rotate next block into current (lgkm wait lands here) ----
#pragma unroll
        for (int k = 0; k < KB; ++k) {
            xc0[k] = xn0[k];
            xc1[k] = xn1[k];
        }
    }
}

// ---------------------------------------------------------------------------
// Kernel 3: logits[pos][v] = h[pos] . w_out[v] + b_out[v]   (R1-R12 proven)
// ---------------------------------------------------------------------------
#define POS_PER_WAVE 16

__global__ __launch_bounds__(256) void out_proj(
    const float* __restrict__ h,      // [B*T][32]
    const float* __restrict__ w_out,  // [128][32]
    const float* __restrict__ b_out,  // [128]
    float*       __restrict__ out)    // [B*T][128]
{
    const int gtid = blockIdx.x * blockDim.x + threadIdx.x;
    const int wave = gtid >> 6;
    const int lane = threadIdx.x & 63;

    float wv0[HID], wv1[HID];
#pragma unroll
    for (int j = 0; j < HID; ++j) {
        wv0[j] = w_out[lane * HID + j];
        wv1[j] = w_out[(lane + 64) * HID + j];
    }
    const float bb0 = b_out[lane];
    const float bb1 = b_out[lane + 64];

    int pos0 = wave * POS_PER_WAVE;
    for (int p = 0; p < POS_PER_WAVE; ++p) {
        int pos = __builtin_amdgcn_readfirstlane(pos0 + p);
        const float* hp = h + (size_t)pos * HID;
        float a0 = bb0, a1 = bb1;
#pragma unroll
        for (int j4 = 0; j4 < HID / 4; ++j4) {
            float4 hv = *reinterpret_cast<const float4*>(hp + 4 * j4);
            a0 = fmaf(hv.x, wv0[4 * j4 + 0], a0);
            a1 = fmaf(hv.x, wv1[4 * j4 + 0], a1);
            a0 = fmaf(hv.y, wv0[4 * j4 + 1], a0);
            a1 = fmaf(hv.y, wv1[4 * j4 + 1], a1);
            a0 = fmaf(hv.z, wv0[4 * j4 + 2], a0);
            a1 = fmaf(hv.z, wv1[4 * j4 + 2], a1);
            a0 = fmaf(hv.w, wv0[4 * j4 + 3], a0);
            a1 = fmaf(hv.w, wv1[4 * j4 + 3], a1);
        }
        out[(size_t)pos * VOCAB + lane]      = a0;
        out[(size_t)pos * VOCAB + 64 + lane] = a1;
    }
}

// ---------------------------------------------------------------------------
extern "C" void kernel_launch(void* const* d_in, const int* in_sizes, int n_in,
                              void* d_out, int out_size, void* d_ws, size_t ws_size,
                              hipStream_t stream) {
    const int*   tokens = (const int*)  d_in[0];
    const float* emb    = (const float*)d_in[1];
    const float* w_ih   = (const float*)d_in[2];
    const float* w_hh   = (const float*)d_in[3];
    const float* b_ih   = (const float*)d_in[4];
    const float* b_hh   = (const float*)d_in[5];
    const float* w_out  = (const float*)d_in[6];
    const float* b_out  = (const float*)d_in[7];
    float*       out    = (float*)d_out;

    float* proj = (float*)d_ws;
    float* hbuf = (float*)((char*)d_ws + VOCAB * G4 * sizeof(float));

    build_proj<<<(VOCAB * G4) / 256, 256, 0, stream>>>(emb, w_ih, b_ih, b_hh, proj);

    lstm_rec<<<BATCH / WPB, 64 * WPB, 0, stream>>>(tokens, w_hh, proj, hbuf);

    const int total_pos = BATCH * SEQ;                    // 262144
    const int waves     = total_pos / POS_PER_WAVE;       // 16384
    out_proj<<<waves / 4, 256, 0, stream>>>(hbuf, w_out, b_out, out);
}

// Round 14
// 188.100 us; speedup vs baseline: 1.4690x; 1.4690x over previous
//
#include <hip/hip_runtime.h>

#define VOCAB 128
#define EMB   8
#define HID   32
#define BATCH 512
#define SEQ   512
#define G4    128   // 4*HID
#define KB    8     // recurrence steps per phase

#define LOG2E 1.4426950408889634f

// ---------------------------------------------------------------------------
// Kernel 1: proj[v][r] = (dot(emb[v], w_ih[r]) + b_ih[r] + b_hh[r]) * rowscale
// rowscale folds exp->exp2: g-rows [64,96): 2*log2e ; others: log2e
// ---------------------------------------------------------------------------
__global__ void build_proj(const float* __restrict__ emb,
                           const float* __restrict__ w_ih,
                           const float* __restrict__ b_ih,
                           const float* __restrict__ b_hh,
                           float* __restrict__ proj) {
    int idx = blockIdx.x * blockDim.x + threadIdx.x;   // 0 .. 16383
    int v = idx >> 7;
    int r = idx & 127;
    float acc = b_ih[r] + b_hh[r];
#pragma unroll
    for (int e = 0; e < EMB; ++e)
        acc += emb[v * EMB + e] * w_ih[r * EMB + e];
    float sc = (r >= 64 && r < 96) ? (2.0f * LOG2E) : LOG2E;
    proj[v * G4 + r] = acc * sc;
}

// ---------------------------------------------------------------------------
// Fast gate nonlinearities (inputs pre-scaled by log2e / 2*log2e). Proven R10.
// ---------------------------------------------------------------------------
__device__ __forceinline__ float sig2(float x) {
    return __builtin_amdgcn_rcpf(1.0f + __builtin_amdgcn_exp2f(-x));
}
__device__ __forceinline__ float tanh2(float x2) {
    return 1.0f - 2.0f * __builtin_amdgcn_rcpf(__builtin_amdgcn_exp2f(x2) + 1.0f);
}

// ---------------------------------------------------------------------------
// Alias-proof half-broadcast (proven R10): early-clobber outputs guarantee
// distinct registers; after the swap, lo = low-half value broadcast to all
// lanes, hi = high-half value broadcast to all lanes.
// ---------------------------------------------------------------------------
__device__ __forceinline__ void half_bcast(float acc, float& lo, float& hi) {
    asm("v_mov_b32 %0, %2\n\t"
        "v_mov_b32 %1, %2\n\t"
        "v_permlane32_swap_b32 %0, %1"
        : "=&v"(lo), "=&v"(hi)
        : "v"(acc));
}

// ---------------------------------------------------------------------------
// Kernel 2: LSTM recurrence. One sequence per wave (512 waves, 2 waves/CU,
// 1 wave/SIMD — proven optimal packing, R13 closed co-residency).
// R12-proven structure. SINGLE DELTA vs R12: all 32 h-readlanes are hoisted
// into a uniform (SGPR) array BEFORE the FMA chains, fenced with
// sched_barrier, so the readlane->SGPR->VALU wait-state hazard is paid once
// per step instead of per 4-FMA group.
// ---------------------------------------------------------------------------
__global__ __launch_bounds__(64)
__attribute__((amdgpu_waves_per_eu(1, 1)))
void lstm_rec(
    const int*   __restrict__ tokens,   // [B][T]
    const float* __restrict__ w_hh,     // [128][32]
    const float* __restrict__ proj,     // [128][128], pre-scaled
    float*       __restrict__ h_out)    // [B*T][32]
{
    const int b    = blockIdx.x;
    const int lane = threadIdx.x;      // 0..63

    __shared__ float sproj[VOCAB * G4];   // 64 KB

    // ---- stage proj into LDS (once) ----
    {
        const float4* src = (const float4*)proj;
        float4*       dst = (float4*)sproj;
#pragma unroll 4
        for (int i = 0; i < (VOCAB * G4 / 4) / 64; ++i)
            dst[i * 64 + lane] = src[i * 64 + lane];
    }

    // ---- recurrent weights: 2 gate rows per lane, pre-scaled, pinned ----
    const float sc1 = (lane < 32) ? (2.0f * LOG2E) : LOG2E;
    float w0[HID], w1[HID];
#pragma unroll
    for (int j = 0; j < HID; ++j) {
        w0[j] = w_hh[lane * HID + j] * LOG2E;
        w1[j] = w_hh[(lane + 64) * HID + j] * sc1;
    }
#pragma unroll
    for (int j = 0; j < HID; ++j) {
        asm volatile("" : "+v"(w0[j]), "+v"(w1[j]));   // non-rematerializable
    }

    // ---- all 512 tokens of this sequence in lane registers ----
    // lane l holds tok[l*8 .. l*8+7]
    const int* tok = tokens + b * SEQ;
    int tv[KB];
    {
        int4 a = ((const int4*)tok)[lane * 2];
        int4 d = ((const int4*)tok)[lane * 2 + 1];
        tv[0] = a.x; tv[1] = a.y; tv[2] = a.z; tv[3] = a.w;
        tv[4] = d.x; tv[5] = d.y; tv[6] = d.z; tv[7] = d.w;
    }

    __syncthreads();

    float h = 0.0f, c = 0.0f;
    float* hp = h_out + (size_t)b * SEQ * HID + lane;   // lanes<32 store
    float hsave[KB];

    // xp double buffer in registers: xc = current block, xn = next block.
    float xc0[KB], xc1[KB];

    // prologue: load block 0 (tokens in lane 0)
#pragma unroll
    for (int k = 0; k < KB; ++k) {
        int tk = __builtin_amdgcn_readlane(tv[k], 0);
        xc0[k] = sproj[tk * G4 + lane];
        xc1[k] = sproj[tk * G4 + 64 + lane];
    }

    for (int t0 = 0; t0 < SEQ; t0 += KB) {
        // ---- phase A: issue next block's 16 ds_reads (wrap to 0 at tail) ----
        const int nb = t0 + KB;
        const int ln = (nb < SEQ) ? (nb >> 3) : 0;   // uniform lane index
        float xn0[KB], xn1[KB];
#pragma unroll
        for (int k = 0; k < KB; ++k) {
            int tk = __builtin_amdgcn_readlane(tv[k], ln);
            xn0[k] = sproj[tk * G4 + lane];
            xn1[k] = sproj[tk * G4 + 64 + lane];
        }
        __builtin_amdgcn_sched_barrier(0);   // loads may not sink below here

        // ---- phase B: 8 recurrence steps, pure register compute ----
#pragma unroll
        for (int k = 0; k < KB; ++k) {
            // hoist ALL h-broadcasts first: back-to-back readlanes pipeline,
            // paying the VALU->readlane hazard once instead of per FMA group
            unsigned hb = __float_as_uint(h);
            float hu[HID];
#pragma unroll
            for (int j = 0; j < HID; ++j)
                hu[j] = __uint_as_float(__builtin_amdgcn_readlane(hb, j));
            __builtin_amdgcn_sched_barrier(0);   // readlanes stay above FMAs

            float s0 = xc0[k], s1 = 0.0f, s2 = 0.0f, s3 = 0.0f;  // row lane
            float u0 = xc1[k], u1 = 0.0f, u2 = 0.0f, u3 = 0.0f;  // row lane+64
#pragma unroll
            for (int j = 0; j < HID; j += 4) {
                s0 = fmaf(hu[j],     w0[j],     s0);
                s1 = fmaf(hu[j + 1], w0[j + 1], s1);
                s2 = fmaf(hu[j + 2], w0[j + 2], s2);
                s3 = fmaf(hu[j + 3], w0[j + 3], s3);
                u0 = fmaf(hu[j],     w1[j],     u0);
                u1 = fmaf(hu[j + 1], w1[j + 1], u1);
                u2 = fmaf(hu[j + 2], w1[j + 2], u2);
                u3 = fmaf(hu[j + 3], w1[j + 3], u3);
            }
            float acc0 = (s0 + s1) + (s2 + s3);  // i (lo lanes) | f (hi lanes)
            float acc1 = (u0 + u1) + (u2 + u3);  // g (lo, *2log2e) | o (hi)

            // ---- alias-proof half broadcast: iv/gv = lo, fv/ov = hi ----
            float iv, fv, gv, ov;
            half_bcast(acc0, iv, fv);
            half_bcast(acc1, gv, ov);

            // ---- nonlinearities (exp2-domain, hw rcp) ----
            c = sig2(fv) * c + sig2(iv) * tanh2(gv);
            h = sig2(ov) * tanh2(c * (2.0f * LOG2E));

            hsave[k] = h;
        }

        // ---- phase C: flush h stores (no vmcnt wait inside the loop) ----
        if (lane < 32) {
#pragma unroll
            for (int k = 0; k < KB; ++k)
                hp[(size_t)(t0 + k) * HID] = hsave[k];
        }

        // ---- phase D: rotate next block into current (lgkm wait lands here) ----
#pragma unroll
        for (int k = 0; k < KB; ++k) {
            xc0[k] = xn0[k];
            xc1[k] = xn1[k];
        }
    }
}

// ---------------------------------------------------------------------------
// Kernel 3: logits[pos][v] = h[pos] . w_out[v] + b_out[v]   (R1-R12 proven)
// ---------------------------------------------------------------------------
#define POS_PER_WAVE 16

__global__ __launch_bounds__(256) void out_proj(
    const float* __restrict__ h,      // [B*T][32]
    const float* __restrict__ w_out,  // [128][32]
    const float* __restrict__ b_out,  // [128]
    float*       __restrict__ out)    // [B*T][128]
{
    const int gtid = blockIdx.x * blockDim.x + threadIdx.x;
    const int wave = gtid >> 6;
    const int lane = threadIdx.x & 63;

    float wv0[HID], wv1[HID];
#pragma unroll
    for (int j = 0; j < HID; ++j) {
        wv0[j] = w_out[lane * HID + j];
        wv1[j] = w_out[(lane + 64) * HID + j];
    }
    const float bb0 = b_out[lane];
    const float bb1 = b_out[lane + 64];

    int pos0 = wave * POS_PER_WAVE;
    for (int p = 0; p < POS_PER_WAVE; ++p) {
        int pos = __builtin_amdgcn_readfirstlane(pos0 + p);
        const float* hp = h + (size_t)pos * HID;
        float a0 = bb0, a1 = bb1;
#pragma unroll
        for (int j4 = 0; j4 < HID / 4; ++j4) {
            float4 hv = *reinterpret_cast<const float4*>(hp + 4 * j4);
            a0 = fmaf(hv.x, wv0[4 * j4 + 0], a0);
            a1 = fmaf(hv.x, wv1[4 * j4 + 0], a1);
            a0 = fmaf(hv.y, wv0[4 * j4 + 1], a0);
            a1 = fmaf(hv.y, wv1[4 * j4 + 1], a1);
            a0 = fmaf(hv.z, wv0[4 * j4 + 2], a0);
            a1 = fmaf(hv.z, wv1[4 * j4 + 2], a1);
            a0 = fmaf(hv.w, wv0[4 * j4 + 3], a0);
            a1 = fmaf(hv.w, wv1[4 * j4 + 3], a1);
        }
        out[(size_t)pos * VOCAB + lane]      = a0;
        out[(size_t)pos * VOCAB + 64 + lane] = a1;
    }
}

// ---------------------------------------------------------------------------
extern "C" void kernel_launch(void* const* d_in, const int* in_sizes, int n_in,
                              void* d_out, int out_size, void* d_ws, size_t ws_size,
                              hipStream_t stream) {
    const int*   tokens = (const int*)  d_in[0];
    const float* emb    = (const float*)d_in[1];
    const float* w_ih   = (const float*)d_in[2];
    const float* w_hh   = (const float*)d_in[3];
    const float* b_ih   = (const float*)d_in[4];
    const float* b_hh   = (const float*)d_in[5];
    const float* w_out  = (const float*)d_in[6];
    const float* b_out  = (const float*)d_in[7];
    float*       out    = (float*)d_out;

    float* proj = (float*)d_ws;
    float* hbuf = (float*)((char*)d_ws + VOCAB * G4 * sizeof(float));

    build_proj<<<(VOCAB * G4) / 256, 256, 0, stream>>>(emb, w_ih, b_ih, b_hh, proj);

    lstm_rec<<<BATCH, 64, 0, stream>>>(tokens, w_hh, proj, hbuf);

    const int total_pos = BATCH * SEQ;                    // 262144
    const int waves     = total_pos / POS_PER_WAVE;       // 16384
    out_proj<<<waves / 4, 256, 0, stream>>>(hbuf, w_out, b_out, out);
}

// Round 15
// 186.892 us; speedup vs baseline: 1.4785x; 1.0065x over previous
//
#include <hip/hip_runtime.h>

#define VOCAB 128
#define EMB   8
#define HID   32
#define BATCH 512
#define SEQ   512
#define G4    128   // 4*HID
#define KB    8     // recurrence steps per phase

#define LOG2E 1.4426950408889634f

typedef float v2f __attribute__((ext_vector_type(2)));

// ---------------------------------------------------------------------------
// Kernel 1: proj[v][r] = (dot(emb[v], w_ih[r]) + b_ih[r] + b_hh[r]) * rowscale
// rowscale folds exp->exp2: g-rows [64,96): 2*log2e ; others: log2e
// ---------------------------------------------------------------------------
__global__ void build_proj(const float* __restrict__ emb,
                           const float* __restrict__ w_ih,
                           const float* __restrict__ b_ih,
                           const float* __restrict__ b_hh,
                           float* __restrict__ proj) {
    int idx = blockIdx.x * blockDim.x + threadIdx.x;   // 0 .. 16383
    int v = idx >> 7;
    int r = idx & 127;
    float acc = b_ih[r] + b_hh[r];
#pragma unroll
    for (int e = 0; e < EMB; ++e)
        acc += emb[v * EMB + e] * w_ih[r * EMB + e];
    float sc = (r >= 64 && r < 96) ? (2.0f * LOG2E) : LOG2E;
    proj[v * G4 + r] = acc * sc;
}

// ---------------------------------------------------------------------------
// Fast gate nonlinearities (inputs pre-scaled by log2e / 2*log2e). Proven R10.
// ---------------------------------------------------------------------------
__device__ __forceinline__ float sig2(float x) {
    return __builtin_amdgcn_rcpf(1.0f + __builtin_amdgcn_exp2f(-x));
}
__device__ __forceinline__ float tanh2(float x2) {
    return 1.0f - 2.0f * __builtin_amdgcn_rcpf(__builtin_amdgcn_exp2f(x2) + 1.0f);
}

// ---------------------------------------------------------------------------
// Alias-proof half-broadcast (proven R10): early-clobber outputs guarantee
// distinct registers; after the swap, lo = low-half value broadcast to all
// lanes, hi = high-half value broadcast to all lanes.
// ---------------------------------------------------------------------------
__device__ __forceinline__ void half_bcast(float acc, float& lo, float& hi) {
    asm("v_mov_b32 %0, %2\n\t"
        "v_mov_b32 %1, %2\n\t"
        "v_permlane32_swap_b32 %0, %1"
        : "=&v"(lo), "=&v"(hi)
        : "v"(acc));
}

// ---------------------------------------------------------------------------
// Kernel 2: LSTM recurrence. One sequence per wave (512 waves, 1 wave/SIMD —
// proven optimal packing). R14-proven structure. SINGLE DELTA vs R14: the
// matvec runs on PACKED dual-FP32 FMAs (v_pk_fma_f32 via
// __builtin_elementwise_fma on float2): 64 scalar FMAs -> 32 packed, and the
// reduction tree packs too. Pairing is even/odd j; each vector lane is
// exactly one of R14's scalar chains (same arithmetic, ~ulp reorder).
// ---------------------------------------------------------------------------
__global__ __launch_bounds__(64)
__attribute__((amdgpu_waves_per_eu(1, 1)))
void lstm_rec(
    const int*   __restrict__ tokens,   // [B][T]
    const float* __restrict__ w_hh,     // [128][32]
    const float* __restrict__ proj,     // [128][128], pre-scaled
    float*       __restrict__ h_out)    // [B*T][32]
{
    const int b    = blockIdx.x;
    const int lane = threadIdx.x;      // 0..63

    __shared__ float sproj[VOCAB * G4];   // 64 KB

    // ---- stage proj into LDS (once) ----
    {
        const float4* src = (const float4*)proj;
        float4*       dst = (float4*)sproj;
#pragma unroll 4
        for (int i = 0; i < (VOCAB * G4 / 4) / 64; ++i)
            dst[i * 64 + lane] = src[i * 64 + lane];
    }

    // ---- recurrent weights as float2 pairs (aligned VGPR pairs), pinned ----
    // w0p[p] = {w_hh[lane][2p],   w_hh[lane][2p+1]}   * log2e      (i|f row)
    // w1p[p] = {w_hh[lane+64][2p],w_hh[lane+64][2p+1]}* sc1        (g|o row)
    const float sc1 = (lane < 32) ? (2.0f * LOG2E) : LOG2E;
    v2f w0p[HID / 2], w1p[HID / 2];
#pragma unroll
    for (int p = 0; p < HID / 2; ++p) {
        w0p[p][0] = w_hh[lane * HID + 2 * p]     * LOG2E;
        w0p[p][1] = w_hh[lane * HID + 2 * p + 1] * LOG2E;
        w1p[p][0] = w_hh[(lane + 64) * HID + 2 * p]     * sc1;
        w1p[p][1] = w_hh[(lane + 64) * HID + 2 * p + 1] * sc1;
    }
#pragma unroll
    for (int p = 0; p < HID / 2; ++p) {
        asm volatile("" : "+v"(w0p[p]), "+v"(w1p[p]));   // non-rematerializable
    }

    // ---- all 512 tokens of this sequence in lane registers ----
    // lane l holds tok[l*8 .. l*8+7]
    const int* tok = tokens + b * SEQ;
    int tv[KB];
    {
        int4 a = ((const int4*)tok)[lane * 2];
        int4 d = ((const int4*)tok)[lane * 2 + 1];
        tv[0] = a.x; tv[1] = a.y; tv[2] = a.z; tv[3] = a.w;
        tv[4] = d.x; tv[5] = d.y; tv[6] = d.z; tv[7] = d.w;
    }

    __syncthreads();

    float h = 0.0f, c = 0.0f;
    float* hp = h_out + (size_t)b * SEQ * HID + lane;   // lanes<32 store
    float hsave[KB];

    // xp double buffer in registers: xc = current block, xn = next block.
    float xc0[KB], xc1[KB];

    // prologue: load block 0 (tokens in lane 0)
#pragma unroll
    for (int k = 0; k < KB; ++k) {
        int tk = __builtin_amdgcn_readlane(tv[k], 0);
        xc0[k] = sproj[tk * G4 + lane];
        xc1[k] = sproj[tk * G4 + 64 + lane];
    }

    for (int t0 = 0; t0 < SEQ; t0 += KB) {
        // ---- phase A: issue next block's 16 ds_reads (wrap to 0 at tail) ----
        const int nb = t0 + KB;
        const int ln = (nb < SEQ) ? (nb >> 3) : 0;   // uniform lane index
        float xn0[KB], xn1[KB];
#pragma unroll
        for (int k = 0; k < KB; ++k) {
            int tk = __builtin_amdgcn_readlane(tv[k], ln);
            xn0[k] = sproj[tk * G4 + lane];
            xn1[k] = sproj[tk * G4 + 64 + lane];
        }
        __builtin_amdgcn_sched_barrier(0);   // loads may not sink below here

        // ---- phase B: 8 recurrence steps, pure register compute ----
#pragma unroll
        for (int k = 0; k < KB; ++k) {
            // hoist all h-broadcasts (uniform pairs for VOP3P operands)
            unsigned hb = __float_as_uint(h);
            v2f hup[HID / 2];
#pragma unroll
            for (int p = 0; p < HID / 2; ++p) {
                hup[p][0] = __uint_as_float(__builtin_amdgcn_readlane(hb, 2 * p));
                hup[p][1] = __uint_as_float(__builtin_amdgcn_readlane(hb, 2 * p + 1));
            }
            __builtin_amdgcn_sched_barrier(0);   // readlanes stay above FMAs

            // packed matvec: 8 float2 chains of depth 4 (32 pk_fma total)
            v2f sA = {xc0[k], 0.0f}, sB = {0.0f, 0.0f},
                sC = {0.0f, 0.0f},   sD = {0.0f, 0.0f};
            v2f uA = {xc1[k], 0.0f}, uB = {0.0f, 0.0f},
                uC = {0.0f, 0.0f},   uD = {0.0f, 0.0f};
#pragma unroll
            for (int p = 0; p < HID / 2; p += 4) {
                sA = __builtin_elementwise_fma(hup[p],     w0p[p],     sA);
                sB = __builtin_elementwise_fma(hup[p + 1], w0p[p + 1], sB);
                sC = __builtin_elementwise_fma(hup[p + 2], w0p[p + 2], sC);
                sD = __builtin_elementwise_fma(hup[p + 3], w0p[p + 3], sD);
                uA = __builtin_elementwise_fma(hup[p],     w1p[p],     uA);
                uB = __builtin_elementwise_fma(hup[p + 1], w1p[p + 1], uB);
                uC = __builtin_elementwise_fma(hup[p + 2], w1p[p + 2], uC);
                uD = __builtin_elementwise_fma(hup[p + 3], w1p[p + 3], uD);
            }
            v2f sS = (sA + sB) + (sC + sD);
            v2f uS = (uA + uB) + (uC + uD);
            float acc0 = sS[0] + sS[1];   // i (lo lanes) | f (hi lanes)
            float acc1 = uS[0] + uS[1];   // g (lo, *2log2e) | o (hi)

            // ---- alias-proof half broadcast: iv/gv = lo, fv/ov = hi ----
            float iv, fv, gv, ov;
            half_bcast(acc0, iv, fv);
            half_bcast(acc1, gv, ov);

            // ---- nonlinearities (exp2-domain, hw rcp) ----
            c = sig2(fv) * c + sig2(iv) * tanh2(gv);
            h = sig2(ov) * tanh2(c * (2.0f * LOG2E));

            hsave[k] = h;
        }

        // ---- phase C: flush h stores (no vmcnt wait inside the loop) ----
        if (lane < 32) {
#pragma unroll
            for (int k = 0; k < KB; ++k)
                hp[(size_t)(t0 + k) * HID] = hsave[k];
        }

        // ---- phase D: rotate next block into current (lgkm wait lands here) ----
#pragma unroll
        for (int k = 0; k < KB; ++k) {
            xc0[k] = xn0[k];
            xc1[k] = xn1[k];
        }
    }
}

// ---------------------------------------------------------------------------
// Kernel 3: logits[pos][v] = h[pos] . w_out[v] + b_out[v]   (R1-R14 proven)
// ---------------------------------------------------------------------------
#define POS_PER_WAVE 16

__global__ __launch_bounds__(256) void out_proj(
    const float* __restrict__ h,      // [B*T][32]
    const float* __restrict__ w_out,  // [128][32]
    const float* __restrict__ b_out,  // [128]
    float*       __restrict__ out)    // [B*T][128]
{
    const int gtid = blockIdx.x * blockDim.x + threadIdx.x;
    const int wave = gtid >> 6;
    const int lane = threadIdx.x & 63;

    float wv0[HID], wv1[HID];
#pragma unroll
    for (int j = 0; j < HID; ++j) {
        wv0[j] = w_out[lane * HID + j];
        wv1[j] = w_out[(lane + 64) * HID + j];
    }
    const float bb0 = b_out[lane];
    const float bb1 = b_out[lane + 64];

    int pos0 = wave * POS_PER_WAVE;
    for (int p = 0; p < POS_PER_WAVE; ++p) {
        int pos = __builtin_amdgcn_readfirstlane(pos0 + p);
        const float* hp = h + (size_t)pos * HID;
        float a0 = bb0, a1 = bb1;
#pragma unroll
        for (int j4 = 0; j4 < HID / 4; ++j4) {
            float4 hv = *reinterpret_cast<const float4*>(hp + 4 * j4);
            a0 = fmaf(hv.x, wv0[4 * j4 + 0], a0);
            a1 = fmaf(hv.x, wv1[4 * j4 + 0], a1);
            a0 = fmaf(hv.y, wv0[4 * j4 + 1], a0);
            a1 = fmaf(hv.y, wv1[4 * j4 + 1], a1);
            a0 = fmaf(hv.z, wv0[4 * j4 + 2], a0);
            a1 = fmaf(hv.z, wv1[4 * j4 + 2], a1);
            a0 = fmaf(hv.w, wv0[4 * j4 + 3], a0);
            a1 = fmaf(hv.w, wv1[4 * j4 + 3], a1);
        }
        out[(size_t)pos * VOCAB + lane]      = a0;
        out[(size_t)pos * VOCAB + 64 + lane] = a1;
    }
}

// ---------------------------------------------------------------------------
extern "C" void kernel_launch(void* const* d_in, const int* in_sizes, int n_in,
                              void* d_out, int out_size, void* d_ws, size_t ws_size,
                              hipStream_t stream) {
    const int*   tokens = (const int*)  d_in[0];
    const float* emb    = (const float*)d_in[1];
    const float* w_ih   = (const float*)d_in[2];
    const float* w_hh   = (const float*)d_in[3];
    const float* b_ih   = (const float*)d_in[4];
    const float* b_hh   = (const float*)d_in[5];
    const float* w_out  = (const float*)d_in[6];
    const float* b_out  = (const float*)d_in[7];
    float*       out    = (float*)d_out;

    float* proj = (float*)d_ws;
    float* hbuf = (float*)((char*)d_ws + VOCAB * G4 * sizeof(float));

    build_proj<<<(VOCAB * G4) / 256, 256, 0, stream>>>(emb, w_ih, b_ih, b_hh, proj);

    lstm_rec<<<BATCH, 64, 0, stream>>>(tokens, w_hh, proj, hbuf);

    const int total_pos = BATCH * SEQ;                    // 262144
    const int waves     = total_pos / POS_PER_WAVE;       // 16384
    out_proj<<<waves / 4, 256, 0, stream>>>(hbuf, w_out, b_out, out);
}